// Round 1
// baseline (1156.453 us; speedup 1.0000x reference)
//
#include <hip/hip_runtime.h>

#define NN 50000
#define DD 128

typedef __attribute__((ext_vector_type(8))) short bf16x8;
typedef __attribute__((ext_vector_type(4))) float f32x4;

static __device__ __forceinline__ unsigned short f2bf(float x) {
    // round-to-nearest-even f32 -> bf16
    unsigned int u = __float_as_uint(x);
    unsigned int r = (u + 0x7fffu + ((u >> 16) & 1u)) >> 16;
    return (unsigned short)r;
}

// Per-edge scatter: 32-lane group per edge, float4 gather of x[col], atomic fadd into agg[row].
__global__ void __launch_bounds__(256) scatter_kernel(
    const float* __restrict__ x,
    const int* __restrict__ row,
    const int* __restrict__ col,
    float* __restrict__ agg,
    int* __restrict__ counts,
    int E)
{
    int gid = blockIdx.x * blockDim.x + threadIdx.x;
    int group = gid >> 5;
    int lane = threadIdx.x & 31;
    int ngroups = (gridDim.x * blockDim.x) >> 5;
    for (int e = group; e < E; e += ngroups) {
        int r = row[e];
        int c = col[e];
        float4 v = reinterpret_cast<const float4*>(x + (size_t)c * DD)[lane];
        float* dst = agg + (size_t)r * DD + lane * 4;
        unsafeAtomicAdd(dst + 0, v.x);
        unsafeAtomicAdd(dst + 1, v.y);
        unsafeAtomicAdd(dst + 2, v.z);
        unsafeAtomicAdd(dst + 3, v.w);
        if (lane == 0) atomicAdd(counts + r, 1);
    }
}

// One-time: W [k][j] fp32 -> Wt [j][k] bf16 (so MFMA B-fragments are contiguous 16B).
__global__ void __launch_bounds__(256) wt_kernel(
    const float* __restrict__ W, unsigned short* __restrict__ Wt)
{
    for (int idx = threadIdx.x; idx < DD * DD; idx += 256) {
        int k = idx >> 7;
        int j = idx & 127;
        Wt[j * DD + k] = f2bf(W[idx]);
    }
}

// Fused mean-scale + Linear(bf16 MFMA) + bias + ReLU. 64 rows/block, 4 waves.
__global__ void __launch_bounds__(256) gemm_kernel(
    const float* __restrict__ agg,
    const int* __restrict__ counts,
    const unsigned short* __restrict__ Wt,
    const float* __restrict__ bias,
    float* __restrict__ out)
{
    __shared__ unsigned short w_lds[DD * DD];   // 32KB bf16, layout [j][k]
    __shared__ unsigned short a_lds[64 * DD];   // 16KB bf16, layout [local_row][k]
    __shared__ float b_lds[DD];

    const int tid = threadIdx.x;
    const int i0 = blockIdx.x * 64;

    // stage Wt into LDS: 32KB = 2048 x 16B
    {
        const uint4* src = reinterpret_cast<const uint4*>(Wt);
        uint4* dst = reinterpret_cast<uint4*>(w_lds);
        #pragma unroll
        for (int it = 0; it < 8; ++it) dst[tid + it * 256] = src[tid + it * 256];
    }
    if (tid < DD) b_lds[tid] = bias[tid];

    // stage A rows: scale by 1/max(count,1), convert to bf16
    #pragma unroll
    for (int it = 0; it < 8; ++it) {
        int idx = tid + it * 256;          // float4 index, 2048 total
        int r = idx >> 5;                  // local row 0..63
        int c4 = idx & 31;
        int grow = i0 + r;
        float4 v = make_float4(0.f, 0.f, 0.f, 0.f);
        float inv = 0.f;
        if (grow < NN) {
            v = reinterpret_cast<const float4*>(agg + (size_t)grow * DD)[c4];
            inv = 1.0f / fmaxf((float)counts[grow], 1.0f);
        }
        ushort4 o;
        o.x = f2bf(v.x * inv); o.y = f2bf(v.y * inv);
        o.z = f2bf(v.z * inv); o.w = f2bf(v.w * inv);
        reinterpret_cast<ushort4*>(a_lds)[idx] = o;
    }
    __syncthreads();

    const int wave = tid >> 6;
    const int lane = tid & 63;
    const int lrow = lane & 15;   // A-row / B-col / D-col within tile
    const int kgrp = lane >> 4;   // 0..3

    // A fragments: rows wave*16 + lrow, k = s*32 + kgrp*8 + e
    bf16x8 afrag[4];
    #pragma unroll
    for (int s = 0; s < 4; ++s) {
        const unsigned short* p = &a_lds[(wave * 16 + lrow) * DD + s * 32 + kgrp * 8];
        afrag[s] = *reinterpret_cast<const bf16x8*>(p);
    }

    f32x4 acc[8];
    #pragma unroll
    for (int t = 0; t < 8; ++t) acc[t] = (f32x4){0.f, 0.f, 0.f, 0.f};

    #pragma unroll
    for (int t = 0; t < 8; ++t) {
        #pragma unroll
        for (int s = 0; s < 4; ++s) {
            const unsigned short* p = &w_lds[(t * 16 + lrow) * DD + s * 32 + kgrp * 8];
            bf16x8 bfrag = *reinterpret_cast<const bf16x8*>(p);
            acc[t] = __builtin_amdgcn_mfma_f32_16x16x32_bf16(afrag[s], bfrag, acc[t], 0, 0, 0);
        }
    }

    // D layout: col = lane&15, row = (lane>>4)*4 + reg   [m89-verified]
    #pragma unroll
    for (int t = 0; t < 8; ++t) {
        int colj = t * 16 + lrow;
        float bb = b_lds[colj];
        #pragma unroll
        for (int r = 0; r < 4; ++r) {
            int grow = i0 + wave * 16 + kgrp * 4 + r;
            if (grow < NN) {
                out[(size_t)grow * DD + colj] = fmaxf(acc[t][r] + bb, 0.f);
            }
        }
    }
}

extern "C" void kernel_launch(void* const* d_in, const int* in_sizes, int n_in,
                              void* d_out, int out_size, void* d_ws, size_t ws_size,
                              hipStream_t stream) {
    const float* x  = (const float*)d_in[0];
    const int* ei   = (const int*)d_in[1];
    const float* W  = (const float*)d_in[2];
    const float* b  = (const float*)d_in[3];
    float* out      = (float*)d_out;

    const int E = in_sizes[1] / 2;

    int* counts = (int*)d_ws;                                   // 50000 ints
    unsigned short* Wt = (unsigned short*)((char*)d_ws + 200192); // 32KB bf16, 16B-aligned

    // agg accumulates in d_out; zero it and the counts every call
    hipMemsetAsync(d_out, 0, (size_t)NN * DD * sizeof(float), stream);
    hipMemsetAsync(counts, 0, (size_t)NN * sizeof(int), stream);

    wt_kernel<<<1, 256, 0, stream>>>(W, Wt);
    scatter_kernel<<<2048, 256, 0, stream>>>(x, ei, ei + E, out, counts, E);
    gemm_kernel<<<(NN + 63) / 64, 256, 0, stream>>>(out, counts, Wt, b, out);
}

// Round 2
// 164.004 us; speedup vs baseline: 7.0514x; 7.0514x over previous
//
#include <hip/hip_runtime.h>

#define NN 50000
#define DD 128
#define NB 196          // ceil(50000/256)

typedef __attribute__((ext_vector_type(8))) short bf16x8;
typedef __attribute__((ext_vector_type(4))) float f32x4;

static __device__ __forceinline__ unsigned short f2bf(float x) {
    unsigned int u = __float_as_uint(x);
    unsigned int r = (u + 0x7fffu + ((u >> 16) & 1u)) >> 16;
    return (unsigned short)r;
}

// ---------- CSR build ----------

__global__ void __launch_bounds__(256) hist_kernel(
    const int* __restrict__ row, int* __restrict__ counts, int E)
{
    int i = blockIdx.x * 256 + threadIdx.x;
    int stride = gridDim.x * 256;
    for (int e = i; e < E; e += stride) atomicAdd(&counts[row[e]], 1);
}

// per-256-chunk exclusive scan; block totals to bsum
__global__ void __launch_bounds__(256) scan_local_kernel(
    const int* __restrict__ counts, int* __restrict__ wptr, int* __restrict__ bsum)
{
    __shared__ int s[256];
    int tid = threadIdx.x;
    int i = blockIdx.x * 256 + tid;
    int v = (i < NN) ? counts[i] : 0;
    s[tid] = v;
    __syncthreads();
    #pragma unroll
    for (int d = 1; d < 256; d <<= 1) {
        int t = (tid >= d) ? s[tid - d] : 0;
        __syncthreads();
        s[tid] += t;
        __syncthreads();
    }
    if (i < NN) wptr[i] = s[tid] - v;        // exclusive within chunk
    if (tid == 255) bsum[blockIdx.x] = s[255];
}

// exclusive scan of the NB block sums (single block)
__global__ void __launch_bounds__(256) scan_bsum_kernel(int* __restrict__ bsum)
{
    __shared__ int s[256];
    int tid = threadIdx.x;
    int v = (tid < NB) ? bsum[tid] : 0;
    s[tid] = v;
    __syncthreads();
    #pragma unroll
    for (int d = 1; d < 256; d <<= 1) {
        int t = (tid >= d) ? s[tid - d] : 0;
        __syncthreads();
        s[tid] += t;
        __syncthreads();
    }
    if (tid < NB) bsum[tid] = s[tid] - v;
}

__global__ void __launch_bounds__(256) scan_add_kernel(
    int* __restrict__ wptr, const int* __restrict__ bsum)
{
    int i = blockIdx.x * 256 + threadIdx.x;
    if (i < NN) wptr[i] += bsum[blockIdx.x];
}

// place each edge's col into its destination-node segment.
// after this, wptr[r] == segment end (start = end - counts[r]).
__global__ void __launch_bounds__(256) edge_scatter_kernel(
    const int* __restrict__ row, const int* __restrict__ col,
    int* __restrict__ wptr, int* __restrict__ edge_col, int E)
{
    int i = blockIdx.x * 256 + threadIdx.x;
    int stride = gridDim.x * 256;
    for (int e = i; e < E; e += stride) {
        int r = row[e];
        int pos = atomicAdd(&wptr[r], 1);
        edge_col[pos] = col[e];
    }
}

// ---------- gather (scatter_mean without atomics) ----------
// one 32-lane group per node; mean fused; agg written f32 (scaled)
__global__ void __launch_bounds__(256) gather_kernel(
    const float* __restrict__ x,
    const int* __restrict__ wptr, const int* __restrict__ counts,
    const int* __restrict__ edge_col,
    float* __restrict__ agg)
{
    int node = blockIdx.x * 8 + (threadIdx.x >> 5);
    int lane = threadIdx.x & 31;
    if (node >= NN) return;
    int cnt = counts[node];
    int end = wptr[node];           // == offsets[node+1] after edge_scatter
    int start = end - cnt;
    float4 acc = make_float4(0.f, 0.f, 0.f, 0.f);
    for (int base = start; base < end; base += 32) {
        int m = min(32, end - base);
        int cl = (base + lane < end) ? edge_col[base + lane] : 0;
        for (int i = 0; i < m; ++i) {
            int c = __shfl(cl, i, 32);
            float4 v = reinterpret_cast<const float4*>(x + (size_t)c * DD)[lane];
            acc.x += v.x; acc.y += v.y; acc.z += v.z; acc.w += v.w;
        }
    }
    float inv = 1.0f / fmaxf((float)cnt, 1.0f);
    reinterpret_cast<float4*>(agg + (size_t)node * DD)[lane] =
        make_float4(acc.x * inv, acc.y * inv, acc.z * inv, acc.w * inv);
}

// ---------- fallback atomic scatter (if ws too small) ----------
__global__ void __launch_bounds__(256) scatter_atomic_kernel(
    const float* __restrict__ x,
    const int* __restrict__ row, const int* __restrict__ col,
    float* __restrict__ agg, int* __restrict__ counts, int E)
{
    int gid = blockIdx.x * blockDim.x + threadIdx.x;
    int group = gid >> 5;
    int lane = threadIdx.x & 31;
    int ngroups = (gridDim.x * blockDim.x) >> 5;
    for (int e = group; e < E; e += ngroups) {
        int r = row[e];
        int c = col[e];
        float4 v = reinterpret_cast<const float4*>(x + (size_t)c * DD)[lane];
        float* dst = agg + (size_t)r * DD + lane * 4;
        unsafeAtomicAdd(dst + 0, v.x);
        unsafeAtomicAdd(dst + 1, v.y);
        unsafeAtomicAdd(dst + 2, v.z);
        unsafeAtomicAdd(dst + 3, v.w);
        if (lane == 0) atomicAdd(counts + r, 1);
    }
}

// ---------- weights: W[k][j] f32 -> Wt[j][k] bf16 ----------
__global__ void __launch_bounds__(256) wt_kernel(
    const float* __restrict__ W, unsigned short* __restrict__ Wt)
{
    for (int idx = threadIdx.x; idx < DD * DD; idx += 256) {
        int k = idx >> 7;
        int j = idx & 127;
        Wt[j * DD + k] = f2bf(W[idx]);
    }
}

// ---------- fused (optional mean-scale) + Linear bf16 MFMA + bias + ReLU ----------
__global__ void __launch_bounds__(256) gemm_kernel(
    const float* __restrict__ agg,
    const int* __restrict__ counts,      // nullptr if agg already mean-scaled
    const unsigned short* __restrict__ Wt,
    const float* __restrict__ bias,
    float* __restrict__ out)
{
    __shared__ unsigned short w_lds[DD * DD];
    __shared__ unsigned short a_lds[64 * DD];
    __shared__ float b_lds[DD];

    const int tid = threadIdx.x;
    const int i0 = blockIdx.x * 64;

    {
        const uint4* src = reinterpret_cast<const uint4*>(Wt);
        uint4* dst = reinterpret_cast<uint4*>(w_lds);
        #pragma unroll
        for (int it = 0; it < 8; ++it) dst[tid + it * 256] = src[tid + it * 256];
    }
    if (tid < DD) b_lds[tid] = bias[tid];

    #pragma unroll
    for (int it = 0; it < 8; ++it) {
        int idx = tid + it * 256;
        int r = idx >> 5;
        int c4 = idx & 31;
        int grow = i0 + r;
        float4 v = make_float4(0.f, 0.f, 0.f, 0.f);
        float inv = 0.f;
        if (grow < NN) {
            v = reinterpret_cast<const float4*>(agg + (size_t)grow * DD)[c4];
            inv = counts ? (1.0f / fmaxf((float)counts[grow], 1.0f)) : 1.0f;
        }
        ushort4 o;
        o.x = f2bf(v.x * inv); o.y = f2bf(v.y * inv);
        o.z = f2bf(v.z * inv); o.w = f2bf(v.w * inv);
        reinterpret_cast<ushort4*>(a_lds)[idx] = o;
    }
    __syncthreads();

    const int wave = tid >> 6;
    const int lane = tid & 63;
    const int lrow = lane & 15;
    const int kgrp = lane >> 4;

    bf16x8 afrag[4];
    #pragma unroll
    for (int s = 0; s < 4; ++s) {
        const unsigned short* p = &a_lds[(wave * 16 + lrow) * DD + s * 32 + kgrp * 8];
        afrag[s] = *reinterpret_cast<const bf16x8*>(p);
    }

    f32x4 acc[8];
    #pragma unroll
    for (int t = 0; t < 8; ++t) acc[t] = (f32x4){0.f, 0.f, 0.f, 0.f};

    #pragma unroll
    for (int t = 0; t < 8; ++t) {
        #pragma unroll
        for (int s = 0; s < 4; ++s) {
            const unsigned short* p = &w_lds[(t * 16 + lrow) * DD + s * 32 + kgrp * 8];
            bf16x8 bfrag = *reinterpret_cast<const bf16x8*>(p);
            acc[t] = __builtin_amdgcn_mfma_f32_16x16x32_bf16(afrag[s], bfrag, acc[t], 0, 0, 0);
        }
    }

    #pragma unroll
    for (int t = 0; t < 8; ++t) {
        int colj = t * 16 + lrow;
        float bb = b_lds[colj];
        #pragma unroll
        for (int r = 0; r < 4; ++r) {
            int grow = i0 + wave * 16 + kgrp * 4 + r;
            if (grow < NN) {
                out[(size_t)grow * DD + colj] = fmaxf(acc[t][r] + bb, 0.f);
            }
        }
    }
}

extern "C" void kernel_launch(void* const* d_in, const int* in_sizes, int n_in,
                              void* d_out, int out_size, void* d_ws, size_t ws_size,
                              hipStream_t stream) {
    const float* x  = (const float*)d_in[0];
    const int* ei   = (const int*)d_in[1];
    const float* W  = (const float*)d_in[2];
    const float* b  = (const float*)d_in[3];
    float* out      = (float*)d_out;

    const int E = in_sizes[1] / 2;
    const int* row = ei;
    const int* col = ei + E;

    // ws layout (all offsets 16B-aligned)
    char* wsc = (char*)d_ws;
    int* counts   = (int*)(wsc + 0);              // 200000 B
    int* wptr     = (int*)(wsc + 200704);         // 200000 B
    int* bsum     = (int*)(wsc + 401408);         // 784 B
    int* edge_col = (int*)(wsc + 402432);         // 2560000 B
    unsigned short* Wt = (unsigned short*)(wsc + 2962432); // 32768 B
    const size_t WS_NEED = 2995200;

    if (ws_size >= WS_NEED) {
        // ---- CSR path (no f32 atomics) ----
        hipMemsetAsync(counts, 0, (size_t)NN * sizeof(int), stream);
        wt_kernel<<<1, 256, 0, stream>>>(W, Wt);
        hist_kernel<<<2500, 256, 0, stream>>>(row, counts, E);
        scan_local_kernel<<<NB, 256, 0, stream>>>(counts, wptr, bsum);
        scan_bsum_kernel<<<1, 256, 0, stream>>>(bsum);
        scan_add_kernel<<<NB, 256, 0, stream>>>(wptr, bsum);
        edge_scatter_kernel<<<2500, 256, 0, stream>>>(row, col, wptr, edge_col, E);
        gather_kernel<<<(NN + 7) / 8, 256, 0, stream>>>(x, wptr, counts, edge_col, out);
        gemm_kernel<<<(NN + 63) / 64, 256, 0, stream>>>(out, nullptr, Wt, b, out);
    } else {
        // ---- fallback: atomic scatter (round-1 behavior) ----
        int* fc = (int*)d_ws;                              // 50000 ints
        unsigned short* fWt = (unsigned short*)(wsc + 200704);
        hipMemsetAsync(d_out, 0, (size_t)NN * DD * sizeof(float), stream);
        hipMemsetAsync(fc, 0, (size_t)NN * sizeof(int), stream);
        wt_kernel<<<1, 256, 0, stream>>>(W, fWt);
        scatter_atomic_kernel<<<2048, 256, 0, stream>>>(x, row, col, out, fc, E);
        gemm_kernel<<<(NN + 63) / 64, 256, 0, stream>>>(out, fc, fWt, b, out);
    }
}